// Round 8
// baseline (232.416 us; speedup 1.0000x reference)
//
#include <hip/hip_runtime.h>
#include <hip/hip_bf16.h>

// JointNet: logp = log_softmax(tanh(enc@We + b_e (+) dec@Wd + b_d) @ Wfc + b_fc), masked.
// B=4 T=256 U=64 V=1024 F=1024 K_proj=512.
// R7 verdict: kernel is PANEL-FEED bound (~10 TB/s effective chip-wide; 2 GB of W
// re-reads with forced BM=64). Schedules R1-R7 all pin at 230-260us.
// R8: INT8 joint GEMM — mfma_i32_32x32x32_i8 (K=32), per-column W scales, A=rint(127*tanh).
// Halves panel bytes (2GB -> 1GB) and halves MFMA count. Wave-private 4-deep B pipeline
// (counted vmcnt(16), no barriers for B); A-super i8 via LDS, 16 lgkm-only barriers.

#define TT 256
#define UU 64
#define VV 1024
#define FF 1024
#define DK 512

typedef __bf16 bf16x8 __attribute__((ext_vector_type(8)));
typedef float  f32x16 __attribute__((ext_vector_type(16)));
typedef int    i32x4v __attribute__((ext_vector_type(4)));
typedef int    i32x16 __attribute__((ext_vector_type(16)));

__device__ __forceinline__ float fast_tanh(float x) {
  float ax = __builtin_fabsf(x);
  float e  = __expf(-2.0f * ax);
  float r  = (1.0f - e) * __builtin_amdgcn_rcpf(1.0f + e);
  return __builtin_copysignf(r, x);
}

// ---- pack enc/dec weights to bf16 frag-major [k8][1024][8]; quantize Wfc to i8 ----
// blocks 0..255: Wenc -> Pen ; 256..511: Wdec -> Pde ; 512..527: Wfc -> Pq + sc
__global__ __launch_bounds__(256)
void prep_w(const float* __restrict__ Wenc, const float* __restrict__ Wdec,
            const float* __restrict__ Wfc,
            __bf16* __restrict__ Pen, __bf16* __restrict__ Pde,
            signed char* __restrict__ Pq, float* __restrict__ sc)
{
  int bi = blockIdx.x;
  int tid = threadIdx.x;
  if (bi < 512) {
    const float* W = (bi < 256) ? Wenc : Wdec;
    __bf16* P = (bi < 256) ? Pen : Pde;
    int base = (bi < 256) ? bi : bi - 256;
    int idx = base * 256 + tid;          // idx = k8*1024 + v   (k8 < 64)
    int k8 = idx >> 10, v = idx & 1023;
    bf16x8 o;
#pragma unroll
    for (int j = 0; j < 8; ++j) o[j] = (__bf16)W[(k8 * 8 + j) * 1024 + v];
    *(bf16x8*)(P + (size_t)idx * 8) = o;
    return;
  }
  // ---- quantize W_fc: 16 blocks x 64 cols; 4 threads per col ----
  __shared__ float mx[4][64];
  __shared__ float smax[64];
  int blk = bi - 512;
  int p = tid >> 6;                      // 0..3
  int c = tid & 63;                      // 0..63
  int v = blk * 64 + c;
  float m = 0.f;
#pragma unroll 8
  for (int k = p * 256; k < p * 256 + 256; ++k)
    m = fmaxf(m, __builtin_fabsf(Wfc[k * 1024 + v]));
  mx[p][c] = m;
  __syncthreads();
  float mm = fmaxf(fmaxf(mx[0][c], mx[1][c]), fmaxf(mx[2][c], mx[3][c]));
  if (p == 0) { smax[c] = mm; sc[v] = (mm > 0.f) ? mm / 127.f : 1.f; }
  __syncthreads();
  float si = (smax[c] > 0.f) ? 127.f / smax[c] : 0.f;
  // phase2: thread p covers k16 in [p*16, p*16+16)
  for (int k16 = p * 16; k16 < p * 16 + 16; ++k16) {
    unsigned int w[4];
#pragma unroll
    for (int g = 0; g < 4; ++g) {
      unsigned int a = 0;
#pragma unroll
      for (int j = 0; j < 4; ++j) {
        float x = Wfc[(k16 * 16 + g * 4 + j) * 1024 + v];
        int q = (int)rintf(x * si);
        q = q > 127 ? 127 : (q < -127 ? -127 : q);
        a |= (unsigned int)(q & 255) << (8 * j);
      }
      w[g] = a;
    }
    *(uint4*)(Pq + ((size_t)k16 * 1024 + v) * 16) = make_uint4(w[0], w[1], w[2], w[3]);
  }
}

// ---------------- projections: pe = enc@We + be, pd = dec@Wd + bd (bf16 MFMA) ----
__global__ __launch_bounds__(256)
void proj_mfma(const float* __restrict__ enc, const float* __restrict__ dec,
               const __bf16* __restrict__ Pen, const __bf16* __restrict__ Pde,
               const float* __restrict__ be, const float* __restrict__ bd,
               float* __restrict__ pe, float* __restrict__ pd)
{
  constexpr int BK = 128;
  __shared__ __align__(16) char As[2][64 * BK * 2];   // 32KB
  const int tid = threadIdx.x;
  const int lane = tid & 63;
  const int wid  = tid >> 6;        // 0..3
  const int l31  = lane & 31;
  const int lhi  = lane >> 5;

  int bi = blockIdx.x;
  const float* X; const __bf16* PW; const float* bias; float* P; int rt, ct;
  if (bi < 64) { X = enc; PW = Pen; bias = be; P = pe; rt = bi >> 2; ct = bi & 3; }
  else { int bj = bi - 64; X = dec; PW = Pde; bias = bd; P = pd; rt = bj >> 2; ct = bj & 3; }
  const int r0 = rt * 64;

  auto fillA = [&](int buf, int kc) {
#pragma unroll
    for (int i = 0; i < 4; ++i) {
      int tau = i * 256 + tid;
      int r = tau >> 4, g = tau & 15;
      int k = kc * BK + g * 8;
      const float4* x4 = (const float4*)(X + (r0 + r) * DK + k);
      float4 a0 = x4[0], a1 = x4[1];
      float xv[8] = {a0.x, a0.y, a0.z, a0.w, a1.x, a1.y, a1.z, a1.w};
      bf16x8 p;
#pragma unroll
      for (int q = 0; q < 8; ++q) p[q] = (__bf16)xv[q];
      *(bf16x8*)(&As[buf][r * (BK * 2) + ((g * 16) ^ ((r & 7) << 4))]) = p;
    }
  };

  f32x16 acc[2][2];
#pragma unroll
  for (int mi = 0; mi < 2; ++mi)
#pragma unroll
    for (int ni = 0; ni < 2; ++ni)
#pragma unroll
      for (int q = 0; q < 16; ++q) acc[mi][ni][q] = 0.f;

  fillA(0, 0);
  __syncthreads();
  const int colBase = ct * 256 + wid * 64 + l31;
  for (int kc = 0; kc < DK / BK; ++kc) {
    if (kc + 1 < DK / BK) fillA((kc + 1) & 1, kc + 1);
    const char* Ab = As[kc & 1];
#pragma unroll 2
    for (int ks = 0; ks < BK / 16; ++ks) {
      int k8 = (kc * 8 + ks) * 2 + lhi;
      bf16x8 bfr[2];
#pragma unroll
      for (int ni = 0; ni < 2; ++ni)
        bfr[ni] = *(const bf16x8*)(PW + ((size_t)k8 * VV + colBase + ni * 32) * 8);
      bf16x8 afr[2];
#pragma unroll
      for (int mi = 0; mi < 2; ++mi) {
        int ra = mi * 32 + l31;
        int kb = ks * 32 + lhi * 16;
        afr[mi] = *(const bf16x8*)(&Ab[ra * (BK * 2) + (kb ^ ((ra & 7) << 4))]);
      }
#pragma unroll
      for (int mi = 0; mi < 2; ++mi)
#pragma unroll
        for (int ni = 0; ni < 2; ++ni)
          acc[mi][ni] = __builtin_amdgcn_mfma_f32_32x32x16_bf16(afr[mi], bfr[ni], acc[mi][ni], 0, 0, 0);
    }
    __syncthreads();
  }
  float bv[2];
#pragma unroll
  for (int ni = 0; ni < 2; ++ni) bv[ni] = bias[colBase + ni * 32];
#pragma unroll
  for (int mi = 0; mi < 2; ++mi)
#pragma unroll
    for (int j = 0; j < 16; ++j) {
      int row = r0 + mi * 32 + (j & 3) + 8 * (j >> 2) + 4 * lhi;
#pragma unroll
      for (int ni = 0; ni < 2; ++ni)
        P[row * VV + colBase + ni * 32] = acc[mi][ni][j] + bv[ni];
    }
}

// ---- main: per-(b,t) block; INT8 GEMM; wave-private 4-deep B pipeline; fused softmax.
__global__ __launch_bounds__(512, 2)
void joint_main(const float* __restrict__ pe, const float* __restrict__ pd,
                const signed char* __restrict__ Pq, const float* __restrict__ sc,
                const float* __restrict__ bfc,
                const int* __restrict__ elens, const int* __restrict__ dlens,
                float* __restrict__ out)
{
  // B chunk: 32 k (2 k16-slices) x 1024 cols i8 = 32KB, 4 buffers = 128KB.
  // A super: 64 k (4 k16-slices) x 64 rows i8 = 4KB, double-buffered = 8KB.
  __shared__ __align__(16) unsigned char Bb[4][32768];
  __shared__ __align__(16) unsigned char Ab[2][4096];
  __shared__ float pr[8][64];
  __shared__ float lseS[64];

  const int blk = blockIdx.x;        // = b*T + t
  const int b = blk >> 8;
  const int t = blk & 255;
  const int tid = threadIdx.x;
  const int elen = elens[b], dlen = dlens[b];
  float* outBase = out + (size_t)blk * (UU * VV);

  if (t >= elen) {                   // whole 64x1024 tile masked -> zeros
    float4 z = {0.f, 0.f, 0.f, 0.f};
#pragma unroll 4
    for (int i = tid; i < UU * VV / 4; i += 512) ((float4*)outBase)[i] = z;
    return;
  }

  const int lane = tid & 63;
  const int wid  = tid >> 6;         // 0..7
  const int l31  = lane & 31;
  const int lhi  = lane >> 5;
  const int colLane = wid * 128 + l31;

  const float* peRow  = pe + (size_t)blk * FF;
  const float* pdBase = pd + (size_t)b * UU * FF;

  // ---- B staging: WAVE-PRIVATE cols [wid*128,+128). 4 x gload_lds 16B per chunk.
  auto stageB = [&](int kc, int buf) {
    const signed char* gp = Pq + (size_t)kc * 32768;     // 2 slices x 16KB
#pragma unroll
    for (int i = 0; i < 4; ++i) {
      int fb = (i >> 1) * 1024 + wid * 128 + (i & 1) * 64;
      __builtin_amdgcn_global_load_lds(
        (const __attribute__((address_space(1))) void*)(gp + ((size_t)fb + lane) * 16),
        (__attribute__((address_space(3))) void*)(&Bb[buf][fb * 16]),
        16, 0, 0);
    }
  };

  // ---- A staging: thread -> (row ar, slice ah>>1, half ah&1); 8 k-values ----
  float4 R0, R1, R2, R3;
  const int ar = tid >> 3;           // row 0..63
  const int ah = tid & 7;
  auto issueA = [&](int s) {
    int k = s * 64 + (ah >> 1) * 16 + (ah & 1) * 8;
    const float4* e4 = (const float4*)(peRow + k);
    const float4* d4 = (const float4*)(pdBase + (size_t)ar * FF + k);
    R0 = e4[0]; R1 = e4[1]; R2 = d4[0]; R3 = d4[1];
  };
  auto commitA = [&](int buf) {
    float hv[8] = {R0.x + R2.x, R0.y + R2.y, R0.z + R2.z, R0.w + R2.w,
                   R1.x + R3.x, R1.y + R3.y, R1.z + R3.z, R1.w + R3.w};
    unsigned int lo = 0, hi = 0;
#pragma unroll
    for (int e = 0; e < 4; ++e) {
      int q = (int)rintf(fast_tanh(hv[e]) * 127.f);
      lo |= (unsigned int)(q & 255) << (8 * e);
    }
#pragma unroll
    for (int e = 0; e < 4; ++e) {
      int q = (int)rintf(fast_tanh(hv[4 + e]) * 127.f);
      hi |= (unsigned int)(q & 255) << (8 * e);
    }
    *(uint2*)(&Ab[buf][(((ah >> 1) << 6) + ar) * 16 + ((ah & 1) << 3)]) =
        make_uint2(lo, hi);
  };

  i32x16 acc[2][4];
#pragma unroll
  for (int mi = 0; mi < 2; ++mi)
#pragma unroll
    for (int ni = 0; ni < 4; ++ni)
#pragma unroll
      for (int q = 0; q < 16; ++q) acc[mi][ni][q] = 0;

  // one K=32 MFMA step per chunk
  auto mstep = [&](const unsigned char* Bp, const unsigned char* Ap, int kcL) {
    i32x4v bfr[4];
#pragma unroll
    for (int ni = 0; ni < 4; ++ni)
      bfr[ni] = *(const i32x4v*)(Bp + ((size_t)(lhi * 1024 + colLane + (ni << 5)) << 4));
    i32x4v afr[2];
#pragma unroll
    for (int mi = 0; mi < 2; ++mi)
      afr[mi] = *(const i32x4v*)(Ap + ((((kcL << 1) + lhi) << 6) + mi * 32 + l31) * 16);
#pragma unroll
    for (int mi = 0; mi < 2; ++mi)
#pragma unroll
      for (int ni = 0; ni < 4; ++ni)
        acc[mi][ni] = __builtin_amdgcn_mfma_i32_32x32x32_i8(afr[mi], bfr[ni], acc[mi][ni], 0, 0, 0);
  };

  // ---- prologue: A0 staged+committed; B0..B2 in flight; publish A0 ----
  issueA(0);
  commitA(0);                        // compiler auto-waits the 4 A loads
  stageB(0, 0); stageB(1, 1); stageB(2, 2);       // 12 outstanding
  asm volatile("s_waitcnt lgkmcnt(0)" ::: "memory");
  __builtin_amdgcn_sched_barrier(0);
  __builtin_amdgcn_s_barrier();
  __builtin_amdgcn_sched_barrier(0);

  // ---- 32 chunk-iters, fully unrolled; steady-state wait = vmcnt(16) ----
#pragma unroll
  for (int kc = 0; kc < 32; ++kc) {
    const int s = kc >> 1;
    if ((kc & 1) == 0 && s + 1 <= 15) {
      issueA(s + 1);
      __builtin_amdgcn_sched_barrier(0);
    }
    if (kc + 3 < 32) {
      stageB(kc + 3, (kc + 3) & 3);
      __builtin_amdgcn_sched_barrier(0);
    }
    if (kc <= 28)      asm volatile("s_waitcnt vmcnt(16)" ::: "memory");
    else if (kc == 29) asm volatile("s_waitcnt vmcnt(12)" ::: "memory");
    else if (kc == 30) asm volatile("s_waitcnt vmcnt(4)"  ::: "memory");
    else               asm volatile("s_waitcnt vmcnt(0)"  ::: "memory");
    __builtin_amdgcn_sched_barrier(0);
    __builtin_amdgcn_s_setprio(1);
    mstep(Bb[kc & 3], Ab[s & 1], kc & 1);
    __builtin_amdgcn_s_setprio(0);
    if ((kc & 1) == 1 && kc < 31) {
      commitA((s + 1) & 1);          // compiler auto-waits A loads (counted FIFO)
      asm volatile("s_waitcnt lgkmcnt(0)" ::: "memory");   // publish A; B rides
      __builtin_amdgcn_sched_barrier(0);
      __builtin_amdgcn_s_barrier();
      __builtin_amdgcn_sched_barrier(0);
    }
  }

  // ---- epilogue: dequant + bias + exp row-sums (max-free; |logit| < 33) ----
  float bias[4], scl[4];
#pragma unroll
  for (int ni = 0; ni < 4; ++ni) {
    bias[ni] = bfc[colLane + ni * 32];
    scl[ni]  = sc[colLane + ni * 32] * (1.f / 127.f);
  }

  float rsum[2][16];
#pragma unroll
  for (int mi = 0; mi < 2; ++mi)
#pragma unroll
    for (int j = 0; j < 16; ++j) {
      float su = 0.f;
#pragma unroll
      for (int ni = 0; ni < 4; ++ni) {
        float v = (float)acc[mi][ni][j] * scl[ni] + bias[ni];
        acc[mi][ni][j] = __float_as_int(v);     // stash logit back in acc
        su += __expf(v);
      }
      rsum[mi][j] = su;
    }
#pragma unroll
  for (int st = 1; st < 32; st <<= 1) {
#pragma unroll
    for (int mi = 0; mi < 2; ++mi)
#pragma unroll
      for (int j = 0; j < 16; ++j)
        rsum[mi][j] += __shfl_xor(rsum[mi][j], st, 64);
  }
#pragma unroll
  for (int mi = 0; mi < 2; ++mi)
#pragma unroll
    for (int j = 0; j < 16; ++j)
      if (l31 == j) {
        int row = mi * 32 + (j & 3) + 8 * (j >> 2) + 4 * lhi;
        pr[wid][row] = rsum[mi][j];
      }
  __syncthreads();
  if (tid < 64) {
    float su = 0.f;
#pragma unroll
    for (int w = 0; w < 8; ++w) su += pr[w][tid];
    lseS[tid] = __logf(su);
  }
  __syncthreads();

#pragma unroll
  for (int mi = 0; mi < 2; ++mi)
#pragma unroll
    for (int j = 0; j < 16; ++j) {
      int row = mi * 32 + (j & 3) + 8 * (j >> 2) + 4 * lhi;
      float l = lseS[row];
      bool valid = row < dlen;
#pragma unroll
      for (int ni = 0; ni < 4; ++ni) {
        float v = valid ? (__int_as_float(acc[mi][ni][j]) - l) : 0.0f;
        outBase[(size_t)row * VV + colLane + ni * 32] = v;
      }
    }
}

extern "C" void kernel_launch(void* const* d_in, const int* in_sizes, int n_in,
                              void* d_out, int out_size, void* d_ws, size_t ws_size,
                              hipStream_t stream)
{
  const float* enc  = (const float*)d_in[0];
  const float* dec  = (const float*)d_in[1];
  const float* Wenc = (const float*)d_in[2];
  const float* benc = (const float*)d_in[3];
  const float* Wdec = (const float*)d_in[4];
  const float* bdec = (const float*)d_in[5];
  const float* Wfc  = (const float*)d_in[6];
  const float* bfc  = (const float*)d_in[7];
  const int* elens  = (const int*)d_in[8];
  const int* dlens  = (const int*)d_in[9];
  float* out = (float*)d_out;

  float* pe = (float*)d_ws;                       // 1024*1024 f32   (4 MB)
  float* pd = pe + 1024 * 1024;                   // 256*1024 f32    (1 MB)
  __bf16* Pen = (__bf16*)(pd + 256 * 1024);       // 512*1024 bf16   (1 MB)
  __bf16* Pde = Pen + 512 * 1024;                 // 512*1024 bf16   (1 MB)
  signed char* Pq = (signed char*)(Pde + 512 * 1024);  // 1024*1024 i8 (1 MB)
  float* sc = (float*)(Pq + 1024 * 1024);         // 1024 f32

  prep_w<<<528, 256, 0, stream>>>(Wenc, Wdec, Wfc, Pen, Pde, Pq, sc);
  proj_mfma<<<80, 256, 0, stream>>>(enc, dec, Pen, Pde, benc, bdec, pe, pd);
  joint_main<<<1024, 512, 0, stream>>>(pe, pd, Pq, sc, bfc, elens, dlens, out);
}